// Round 6
// baseline (2459.928 us; speedup 1.0000x reference)
//
#include <hip/hip_runtime.h>
#include <hip/hip_bf16.h>

// ---------------------------------------------------------------------------
// Hypernetwork ResNet, bf16x3-split MFMA (fp32-equivalent precision).
// Stage 1 (16ch): fp32 NHWC global, LDS split, 16x16x32 MFMA.
// Stages 2/3 (32/64ch): PADDED bf16x3 activation planes in global; conv_mx
//   reads A/B fragments directly from global (no LDS), 32x32x16 MFMA.
// R5->R6: conv_mx K-loop deepened to 4-stage circular register pipeline
//   (fully unrolled, static indexing); stage-3/transition waves split to
//   NTW=1 (one 32-cout tile per wave) -> 2x wave count. Attacks the
//   MfmaUtil=13% latency stall (loads-in-flight 6 -> ~18 per wave).
// ---------------------------------------------------------------------------

typedef __attribute__((ext_vector_type(8))) short bf16x8;
typedef __attribute__((ext_vector_type(4))) float f32x4;
typedef __attribute__((ext_vector_type(16))) float f32x16;
typedef unsigned short ushort_t;

#define OFFS_LIST {0,1,2,3,4,5,6,7,8,9,10,11,12,14,18,22,26,30,34,38,42,46,50,54,58,66,82,98,114,130,146,162,178,194,210,226,242}
#define K_LIST    {1,1,1,1,1,1,1,1,1,1,1,1,1,2,2,2,2,2,2,2,2,2,2,2,2,4,4,4,4,4,4,4,4,4,4,4}
#define H_LIST    {1,1,1,1,1,1,1,1,1,1,1,1,2,2,2,2,2,2,2,2,2,2,2,2,4,4,4,4,4,4,4,4,4,4,4,4}
#define WOFF_LIST {0,2304,4608,6912,9216,11520,13824,16128,18432,20736,23040,25344,27648,32256,41472,50688,59904,69120,78336,87552,96768,105984,115200,124416,133632,152064,188928,225792,262656,299520,336384,373248,410112,446976,483840,520704}
#define CIN_LIST  {16,16,16,16,16,16,16,16,16,16,16,16,16,32,32,32,32,32,32,32,32,32,32,32,32,64,64,64,64,64,64,64,64,64,64,64}
#define COUT_LIST {16,16,16,16,16,16,16,16,16,16,16,16,32,32,32,32,32,32,32,32,32,32,32,32,64,64,64,64,64,64,64,64,64,64,64,64}
// frag offsets (shorts): L0..13 16x16 format, L14+ 32x32 format,
// L25 has +2 appended residual k-steps. L13 size = 9*2*3*512 = 27648.
#define WFOFF_LIST {0,7680,15360,23040,30720,38400,46080,53760,61440,69120,76800,84480,92160,107520,135168,165888,196608,227328,258048,288768,319488,350208,380928,411648,442368,503808,632832,755712,878592,1001472,1124352,1247232,1370112,1492992,1615872,1738752}

__constant__ int d_offs[37]  = OFFS_LIST;
__constant__ int d_k[36]     = K_LIST;
__constant__ int d_hh[36]    = H_LIST;
__constant__ int d_woff[36]  = WOFF_LIST;
__constant__ int d_cin[36]   = CIN_LIST;
__constant__ int d_cout[36]  = COUT_LIST;
__constant__ int d_wfoff[36] = WFOFF_LIST;

__device__ inline void split3(float x, ushort_t& h, ushort_t& m, ushort_t& l) {
    unsigned xb = __float_as_uint(x);
    unsigned hb = (xb + 0x8000u) >> 16;
    float fh = __uint_as_float(hb << 16);
    float r = x - fh;
    unsigned mb = (__float_as_uint(r) + 0x8000u) >> 16;
    float fm = __uint_as_float(mb << 16);
    float r2 = r - fm;
    unsigned lb = (__float_as_uint(r2) + 0x8000u) >> 16;
    h = (ushort_t)hb; m = (ushort_t)mb; l = (ushort_t)lb;
}
__device__ inline float b2f(ushort_t u) { return __uint_as_float(((unsigned)u) << 16); }

// --- prep: BN scale/shift, rwT6 transpose, shp25 = bnsh[26] + res_b12 -------
__global__ void prep(const float* __restrict__ g, const float* __restrict__ be,
                     const float* __restrict__ m, const float* __restrict__ v,
                     const float* __restrict__ rw6, const float* __restrict__ rb12,
                     float* __restrict__ sc, float* __restrict__ sh,
                     float* __restrict__ rwT6, float* __restrict__ shp25) {
    int i = blockIdx.x * blockDim.x + threadIdx.x;
    if (i < 2368) {
        float s = g[i] * rsqrtf(v[i] + 1e-5f);
        sc[i] = s;
        sh[i] = be[i] - m[i] * s;
    } else if (i < 2368 + 512) {
        int t = i - 2368;
        int co = t % 32, ci = t / 32;
        rwT6[ci * 32 + co] = rw6[co * 16 + ci];
    } else if (i < 2368 + 512 + 64) {
        int c = i - 2880;
        int idx2 = 26 * 64 + c;
        float s = g[idx2] * rsqrtf(v[idx2] + 1e-5f);
        shp25[c] = be[idx2] - m[idx2] * s + rb12[c];
    }
}

// --- Hypernetwork: one block per z-row. Emits fp32 weights [k][co]. ---------
__global__ void hyper_kernel(const float* __restrict__ z_all, const float* __restrict__ w2,
                             const float* __restrict__ b2, const float* __restrict__ w1,
                             const float* __restrict__ b1, const float* __restrict__ bnsc,
                             float* __restrict__ Wg) {
    int n = blockIdx.x;
    int tid = threadIdx.x;
    __shared__ float zrow[64];
    __shared__ float hin[1024];
    if (tid < 64) zrow[tid] = z_all[n * 64 + tid];
    __syncthreads();
    for (int mcol = tid; mcol < 1024; mcol += 256) {
        float acc = b2[mcol];
        #pragma unroll 8
        for (int d = 0; d < 64; ++d) acc += zrow[d] * w2[d * 1024 + mcol];
        hin[mcol] = acc;
    }
    __syncthreads();
    int L = 0;
    while (n >= d_offs[L + 1]) ++L;
    int r = n - d_offs[L];
    int kk = d_k[L];
    int a = r / kk, bb = r % kk;
    int Cin = kk * 16;
    int Cout = d_hh[L] * 16;
    const float* scp = bnsc + (L + 1) * 64;
    float* wp = Wg + d_woff[L];
    for (int e = tid; e < 2304; e += 256) {
        int i = e / 144, o = e % 144;
        int j = o / 9, tap = o % 9;
        float acc = b1[o];
        #pragma unroll 8
        for (int d = 0; d < 64; ++d) acc += hin[i * 64 + d] * w1[d * 144 + o];
        int co = a * 16 + i;
        acc *= scp[co];
        wp[(tap * Cin + (bb * 16 + j)) * Cout + co] = acc;
    }
}

// --- split weights into bf16x3 fragment blocks (two formats) ----------------
__global__ void split_w(const float* __restrict__ Wg, const float* __restrict__ rw12,
                        ushort_t* __restrict__ Wf) {
    int L = blockIdx.y;
    int CIN = d_cin[L], COUT = d_cout[L];
    int idx = blockIdx.x * 256 + threadIdx.x;
    int j = idx & 7, lane = (idx >> 3) & 63, t = idx >> 9;
    int hi = lane >> 5;
    float wv;
    int base;
    if (L < 14) {                       // 16x16x32 fragment format
        int K = 9 * CIN, NKS = (K + 31) / 32, NT = COUT / 16;
        if (t >= NKS * NT) return;
        int nt = t % NT, ks = t / NT;
        int k = ks * 32 + (lane >> 4) * 8 + j;
        int co = nt * 16 + (lane & 15);
        wv = (k < K) ? Wg[d_woff[L] + k * COUT + co] : 0.f;
        base = d_wfoff[L] + ((ks * NT + nt) * 3) * 512 + lane * 8 + j;
    } else {                            // 32x32x16, padded taps (10), tap-inner
        int CG8 = CIN / 8, NKS = 5 * CG8, NT = COUT / 32;
        int TKS = NKS + ((L == 25) ? 2 : 0);
        if (t >= TKS * NT) return;
        int nt = t % NT, ks = t / NT;
        int co = nt * 32 + (lane & 31);
        if (ks < NKS) {
            int o = 2 * ks + hi, tap = o % 10, c8 = o / 10;
            int ci = c8 * 8 + j;
            wv = (tap < 9) ? Wg[d_woff[L] + (tap * CIN + ci) * COUT + co] : 0.f;
        } else {                        // L25 appended 1x1-s2 residual weights
            int k = (ks - NKS) * 16 + hi * 8 + j;
            wv = rw12[co * 32 + k];
        }
        base = d_wfoff[L] + ((ks * NT + nt) * 3) * 512 + lane * 8 + j;
    }
    ushort_t h, m, l;
    split3(wv, h, m, l);
    Wf[base] = h; Wf[base + 512] = m; Wf[base + 1024] = l;
}

// --- First conv: 3->16, NCHW in -> NHWC fp32 out ----------------------------
__global__ void conv_first(const float* __restrict__ x, const float* __restrict__ cw,
                           const float* __restrict__ cb, const float* __restrict__ g,
                           const float* __restrict__ be, const float* __restrict__ m,
                           const float* __restrict__ v, float* __restrict__ out) {
    int idx = blockIdx.x * 256 + threadIdx.x;
    int px = idx & 31; int t = idx >> 5;
    int py = t & 31;   int b = t >> 5;
    float acc[16];
    #pragma unroll
    for (int co = 0; co < 16; ++co) acc[co] = 0.f;
    const float* ip = x + (long)b * 3 * 1024;
    #pragma unroll 1
    for (int ci = 0; ci < 3; ++ci) {
        #pragma unroll 1
        for (int ky = 0; ky < 3; ++ky) {
            int iy = py + ky - 1;
            if ((unsigned)iy >= 32u) continue;
            #pragma unroll
            for (int kx = 0; kx < 3; ++kx) {
                int ix = px + kx - 1;
                if ((unsigned)ix < 32u) {
                    float xv = ip[ci * 1024 + iy * 32 + ix];
                    #pragma unroll
                    for (int co = 0; co < 16; ++co)
                        acc[co] += xv * cw[co * 27 + ci * 9 + ky * 3 + kx];
                }
            }
        }
    }
    long o = ((long)(b * 32 + py) * 32 + px) * 16;
    #pragma unroll
    for (int co = 0; co < 16; ++co) {
        float s = g[co] * rsqrtf(v[co] + 1e-5f);
        float val = (acc[co] + cb[co] - m[co]) * s + be[co];
        out[o + co] = fmaxf(val, 0.f);
    }
}

// --- zero the halo of a padded plane buffer ---------------------------------
__global__ void pad_zero(ushort_t* __restrict__ buf, int H2, int pxc /*16B chunks*/) {
    int idx = blockIdx.x * 256 + threadIdx.x;
    int nb = 2 * H2 + 2 * (H2 - 2);
    int total = 1024 * nb * pxc;
    if (idx >= total) return;
    int ch = idx % pxc; int t = idx / pxc;
    int bp = t % nb; int img = t / nb;
    int y, x;
    if (bp < H2) { y = 0; x = bp; }
    else if (bp < 2 * H2) { y = H2 - 1; x = bp - H2; }
    else { int s = bp - 2 * H2; y = 1 + (s >> 1); x = (s & 1) ? H2 - 1 : 0; }
    long off = ((long)img * H2 * H2 + y * H2 + x) * (pxc * 8) + ch * 8;
    uint4 z = make_uint4(0, 0, 0, 0);
    *(uint4*)(buf + off) = z;
}

// --- Stage-1 conv: 16x16x32 MFMA, LDS bf16x3 --------------------------------
// MODE 0: relu(conv+sh) | 1: +res fp32 | 2: +1x1s2(res fp32; rwT,rb)
// OUTF 0: fp32 NHWC out | 1: S2 padded planes out (18x18x32)
template<int CIN, int COUT, int HIN, int STRIDE, int TH, int TW, int MODE, int CR, int HR, int OUTF>
__global__ __launch_bounds__(256) void conv_mfma(
        const float* __restrict__ in, const ushort_t* __restrict__ wf,
        const float* __restrict__ shp, const float* __restrict__ res,
        const float* __restrict__ rwT, const float* __restrict__ rb,
        float* __restrict__ out, ushort_t* __restrict__ outp2) {
    constexpr int HOUT = HIN / STRIDE;
    constexpr int CG8 = CIN / 8;
    constexpr int IH = (TH - 1) * STRIDE + 3;
    constexpr int IW = (TW - 1) * STRIDE + 3;
    constexpr int K = 9 * CIN;
    constexpr int NKS = (K + 31) / 32;
    constexpr bool TAIL = (K % 32) != 0;
    constexpr int NT = COUT / 16;
    constexpr int NMT = TH * TW / 16;
    constexpr int MTW = NMT / 4;
    constexpr int PADC = ((2 - (IH * IW)) % 8 + 8) % 8;
    constexpr int CSTU = IH * IW + PADC;
    constexpr int PST = CG8 * CSTU;
    constexpr int TX = HOUT / TW, TY = HOUT / TH;

    __shared__ uint4 lds[3 * PST];

    int tid = threadIdx.x;
    int bid = blockIdx.x;
    int tile = bid % (TY * TX);
    int b = bid / (TY * TX);
    int ty = tile / TX, tx = tile % TX;
    int Y0 = ty * TH, X0 = tx * TW;
    int gy0 = Y0 * STRIDE - 1, gx0 = X0 * STRIDE - 1;

    for (int e = tid; e < CG8 * IH * IW; e += 256) {
        int c8 = e / (IH * IW); int rr = e % (IH * IW);
        int ly = rr / IW, lx = rr % IW;
        int gy = gy0 + ly, gx = gx0 + lx;
        float vv[8];
        if ((unsigned)gy < (unsigned)HIN && (unsigned)gx < (unsigned)HIN) {
            const float4* p = (const float4*)(in + ((long)(b * HIN + gy) * HIN + gx) * CIN + c8 * 8);
            float4 a0 = p[0], a1 = p[1];
            vv[0]=a0.x; vv[1]=a0.y; vv[2]=a0.z; vv[3]=a0.w;
            vv[4]=a1.x; vv[5]=a1.y; vv[6]=a1.z; vv[7]=a1.w;
        } else {
            #pragma unroll
            for (int q = 0; q < 8; ++q) vv[q] = 0.f;
        }
        union { ushort_t u[8]; uint4 q4; } H, M, L;
        #pragma unroll
        for (int q = 0; q < 8; ++q) split3(vv[q], H.u[q], M.u[q], L.u[q]);
        int a16 = c8 * CSTU + rr;
        lds[a16] = H.q4; lds[PST + a16] = M.q4; lds[2 * PST + a16] = L.q4;
    }
    __syncthreads();

    int lane = tid & 63, wid = tid >> 6;
    int g = lane >> 4, r16 = lane & 15;

    f32x4 acc[MTW][NT] = {};

    int pbase[MTW];
    #pragma unroll
    for (int mt = 0; mt < MTW; ++mt) {
        int pid = (wid + 4 * mt) * 16 + r16;
        int py = pid / TW, px = pid % TW;
        pbase[mt] = (py * STRIDE) * IW + px * STRIDE;
    }

    #pragma unroll
    for (int ks = 0; ks < NKS; ++ks) {
        bf16x8 bfr[NT][3];
        #pragma unroll
        for (int nt = 0; nt < NT; ++nt)
            #pragma unroll
            for (int p = 0; p < 3; ++p)
                bfr[nt][p] = *(const bf16x8*)(wf + ((ks * NT + nt) * 3 + p) * 512 + lane * 8);

        int k0 = ks * 32 + g * 8;
        int tap = k0 / CIN;
        int ci8 = (k0 % CIN) >> 3;
        int ky = (tap * 11) >> 5;
        int kx = tap - 3 * ky;
        int ofs = ci8 * CSTU + ky * IW + kx;

        #pragma unroll
        for (int mt = 0; mt < MTW; ++mt) {
            int e16 = ofs + pbase[mt];
            if (TAIL && ks == NKS - 1) e16 = (g < 2) ? e16 : 0;
            const uint4* ap = lds + e16;
            bf16x8 ah = *(const bf16x8*)(ap);
            bf16x8 am = *(const bf16x8*)(ap + PST);
            bf16x8 al = *(const bf16x8*)(ap + 2 * PST);
            #pragma unroll
            for (int nt = 0; nt < NT; ++nt) {
                f32x4 c = acc[mt][nt];
                c = __builtin_amdgcn_mfma_f32_16x16x32_bf16(ah, bfr[nt][0], c, 0, 0, 0);
                c = __builtin_amdgcn_mfma_f32_16x16x32_bf16(ah, bfr[nt][1], c, 0, 0, 0);
                c = __builtin_amdgcn_mfma_f32_16x16x32_bf16(am, bfr[nt][0], c, 0, 0, 0);
                c = __builtin_amdgcn_mfma_f32_16x16x32_bf16(ah, bfr[nt][2], c, 0, 0, 0);
                c = __builtin_amdgcn_mfma_f32_16x16x32_bf16(am, bfr[nt][1], c, 0, 0, 0);
                c = __builtin_amdgcn_mfma_f32_16x16x32_bf16(al, bfr[nt][0], c, 0, 0, 0);
                acc[mt][nt] = c;
            }
        }
    }

    #pragma unroll
    for (int mt = 0; mt < MTW; ++mt) {
        #pragma unroll
        for (int nt = 0; nt < NT; ++nt) {
            int co = nt * 16 + r16;
            float shv = shp[co];
            #pragma unroll
            for (int reg = 0; reg < 4; ++reg) {
                int pid = (wid + 4 * mt) * 16 + g * 4 + reg;
                int py = pid / TW, px = pid % TW;
                int gy = Y0 + py, gx = X0 + px;
                float val = acc[mt][nt][reg] + shv;
                if (MODE == 1) {
                    long oidx = ((long)(b * HOUT + gy) * HOUT + gx) * COUT + co;
                    val += res[oidx];
                }
                if (MODE == 2) {
                    float racc = rb[co];
                    const float* rp = res + ((long)(b * HR + 2 * gy) * HR + 2 * gx) * CR;
                    #pragma unroll 4
                    for (int ci = 0; ci < CR; ++ci) racc += rp[ci] * rwT[ci * COUT + co];
                    val += racc;
                }
                val = fmaxf(val, 0.f);
                if (OUTF == 0) {
                    long oidx = ((long)(b * HOUT + gy) * HOUT + gx) * COUT + co;
                    out[oidx] = val;
                } else {
                    ushort_t* pp = outp2 + (long)b * 31104
                                   + ((gy + 1) * 18 + gx + 1) * 96 + (co >> 3) * 24 + (co & 7);
                    ushort_t h, m2, l;
                    split3(val, h, m2, l);
                    pp[0] = h; pp[8] = m2; pp[16] = l;
                }
            }
        }
    }
}

// --- Stages 2/3: 32x32x16 MFMA, direct-global bf16x3 planes, no LDS ---------
// MODE 0: none | 1: res-add (planes). RKS>0: appended residual k-steps
// reading res planes (RH2, RPXI geometry) at (2y+1, 2x+1).
// NTW: 32-cout tiles per wave; waves split the COUT dimension.
// 4-deep circular register pipeline, fully unrolled (static indexing).
template<int CIN, int COUT, int HIN, int STRIDE, int MODE, int RKS, int RH2, int RPXI, int NTW>
__global__ __launch_bounds__(256) void conv_mx(
        const ushort_t* __restrict__ in, const ushort_t* __restrict__ wf,
        const float* __restrict__ shp, const ushort_t* __restrict__ res,
        ushort_t* __restrict__ out) {
    constexpr int CG8 = CIN / 8;
    constexpr int NKS = 5 * CG8;
    constexpr int TKS = NKS + RKS;
    constexpr int HOUT = HIN / STRIDE, H2I = HIN + 2, H2O = HOUT + 2;
    constexpr int PXI = CIN * 3, PXO = COUT * 3;
    constexpr long IMGI = (long)H2I * H2I * PXI, IMGO = (long)H2O * H2O * PXO;
    constexpr int NTT = COUT / 32;          // total 32-cout tiles
    constexpr int NSP = NTT / NTW;          // cout splits across waves
    constexpr int MT = HOUT * HOUT / 32;
    constexpr int D = 4;                    // pipeline depth

    int tid = threadIdx.x, lane = tid & 63, wid = tid >> 6;
    int wg = blockIdx.x * 4 + wid;
    int img = wg / (MT * NSP);
    int rem = wg % (MT * NSP);
    int mt = rem / NSP, ns = rem % NSP;
    int ntb = ns * NTW;
    int lp = lane & 31, hi = lane >> 5;
    int pix = mt * 32 + lp;
    int py = pix / HOUT, px = pix % HOUT;

    const ushort_t* abase = in + (long)img * IMGI + ((py * STRIDE) * H2I + px * STRIDE) * PXI;
    const ushort_t* rbase = (RKS > 0)
        ? res + (long)img * ((long)RH2 * RH2 * RPXI) + ((2 * py + 1) * RH2 + (2 * px + 1)) * RPXI
        : nullptr;
    const ushort_t* wfl = wf + lane * 8;

    f32x16 acc[NTW] = {};
    bf16x8 xP[D][3];
    bf16x8 wP[D][NTW][3];

    auto LK = [&](int ks, int slot) {
        const ushort_t* ap;
        if (RKS > 0 && ks >= NKS) {
            int c8 = 2 * (ks - NKS) + hi;
            ap = rbase + c8 * 24;
        } else {
            int o = 2 * ks + hi;
            int tap = o % 10, c8 = o / 10;
            int ky = (tap * 11) >> 5, kx = tap - 3 * ky;
            int aofs = (ky * H2I + kx) * PXI + c8 * 24;
            if (tap == 9) aofs = 0;          // zero weights there; any valid addr
            ap = abase + aofs;
        }
        xP[slot][0] = *(const bf16x8*)(ap);
        xP[slot][1] = *(const bf16x8*)(ap + 8);
        xP[slot][2] = *(const bf16x8*)(ap + 16);
        #pragma unroll
        for (int nt = 0; nt < NTW; ++nt)
            #pragma unroll
            for (int p = 0; p < 3; ++p)
                wP[slot][nt][p] = *(const bf16x8*)(wfl + ((ks * NTT + ntb + nt) * 3 + p) * 512);
    };
    auto DO = [&](int slot) {
        #pragma unroll
        for (int nt = 0; nt < NTW; ++nt) {
            f32x16 c = acc[nt];
            c = __builtin_amdgcn_mfma_f32_32x32x16_bf16(wP[slot][nt][0], xP[slot][0], c, 0, 0, 0);
            c = __builtin_amdgcn_mfma_f32_32x32x16_bf16(wP[slot][nt][1], xP[slot][0], c, 0, 0, 0);
            c = __builtin_amdgcn_mfma_f32_32x32x16_bf16(wP[slot][nt][0], xP[slot][1], c, 0, 0, 0);
            c = __builtin_amdgcn_mfma_f32_32x32x16_bf16(wP[slot][nt][2], xP[slot][0], c, 0, 0, 0);
            c = __builtin_amdgcn_mfma_f32_32x32x16_bf16(wP[slot][nt][1], xP[slot][1], c, 0, 0, 0);
            c = __builtin_amdgcn_mfma_f32_32x32x16_bf16(wP[slot][nt][0], xP[slot][2], c, 0, 0, 0);
            acc[nt] = c;
        }
    };

    LK(0, 0); LK(1, 1); LK(2, 2);
    #pragma unroll
    for (int ks = 0; ks < TKS; ++ks) {
        if (ks + 3 < TKS) LK(ks + 3, (ks + 3) & 3);
        DO(ks & 3);
    }

    // epilogue: D col = lane&31 = pixel; row = (reg&3)+8*(reg>>2)+4*hi = cout
    ushort_t* ob = out + (long)img * IMGO + ((py + 1) * H2O + (px + 1)) * PXO;
    const ushort_t* rs = (MODE == 1)
        ? res + (long)img * IMGO + ((py + 1) * H2O + (px + 1)) * PXO : nullptr;
    #pragma unroll
    for (int nt = 0; nt < NTW; ++nt) {
        int ntg = ntb + nt;
        #pragma unroll
        for (int q = 0; q < 4; ++q) {
            int cob = ntg * 32 + q * 8 + 4 * hi;
            float v[4];
            #pragma unroll
            for (int t = 0; t < 4; ++t) v[t] = acc[nt][4 * q + t] + shp[cob + t];
            if (MODE == 1) {
                const ushort_t* rp = rs + (ntg * 4 + q) * 24 + 4 * hi;
                ushort4 rh = *(const ushort4*)(rp);
                ushort4 rm = *(const ushort4*)(rp + 8);
                ushort4 rl = *(const ushort4*)(rp + 16);
                v[0] += b2f(rh.x) + b2f(rm.x) + b2f(rl.x);
                v[1] += b2f(rh.y) + b2f(rm.y) + b2f(rl.y);
                v[2] += b2f(rh.z) + b2f(rm.z) + b2f(rl.z);
                v[3] += b2f(rh.w) + b2f(rm.w) + b2f(rl.w);
            }
            ushort4 h4, m4, l4;
            #pragma unroll
            for (int t = 0; t < 4; ++t) {
                float val = fmaxf(v[t], 0.f);
                ushort_t h, m2, l;
                split3(val, h, m2, l);
                ((ushort_t*)&h4)[t] = h; ((ushort_t*)&m4)[t] = m2; ((ushort_t*)&l4)[t] = l;
            }
            ushort_t* pp = ob + (ntg * 4 + q) * 24 + 4 * hi;
            *(ushort4*)(pp) = h4;
            *(ushort4*)(pp + 8) = m4;
            *(ushort4*)(pp + 16) = l4;
        }
    }
}

// --- avgpool (8x8, S3 planes) + FC (64->10) ---------------------------------
__global__ void pool_fc(const ushort_t* __restrict__ X, const float* __restrict__ fw,
                        const float* __restrict__ fb, float* __restrict__ out) {
    int b = blockIdx.x;
    int c = threadIdx.x;
    const ushort_t* ib = X + (long)b * 19200 + (c >> 3) * 24 + (c & 7);
    float s = 0.f;
    #pragma unroll
    for (int p = 0; p < 64; ++p) {
        int y = p >> 3, x = p & 7;
        int base = ((y + 1) * 10 + (x + 1)) * 192;
        s += b2f(ib[base]) + b2f(ib[base + 8]) + b2f(ib[base + 16]);
    }
    __shared__ float pooled[64];
    pooled[c] = s * (1.f / 64.f);
    __syncthreads();
    if (c < 10) {
        float acc = fb[c];
        #pragma unroll
        for (int k = 0; k < 64; ++k) acc += pooled[k] * fw[c * 64 + k];
        out[b * 10 + c] = acc;
    }
}

extern "C" void kernel_launch(void* const* d_in, const int* in_sizes, int n_in,
                              void* d_out, int out_size, void* d_ws, size_t ws_size,
                              hipStream_t stream) {
    const float* x       = (const float*)d_in[0];
    const float* conv1_w = (const float*)d_in[1];
    const float* conv1_b = (const float*)d_in[2];
    const float* bn_g    = (const float*)d_in[3];
    const float* bn_b    = (const float*)d_in[4];
    const float* bn_m    = (const float*)d_in[5];
    const float* bn_v    = (const float*)d_in[6];
    const float* hn_w2   = (const float*)d_in[7];
    const float* hn_b2   = (const float*)d_in[8];
    const float* hn_w1   = (const float*)d_in[9];
    const float* hn_b1   = (const float*)d_in[10];
    const float* z_all   = (const float*)d_in[11];
    const float* res_w6  = (const float*)d_in[12];
    const float* res_b6  = (const float*)d_in[13];
    const float* res_w12 = (const float*)d_in[14];
    const float* res_b12 = (const float*)d_in[15];
    const float* fin_w   = (const float*)d_in[16];
    const float* fin_b   = (const float*)d_in[17];
    float* outp = (float*)d_out;

    float* wsf      = (float*)d_ws;
    float* Wg       = wsf;                     // 557568 fp32
    float* bnsc     = wsf + 557568;            // 2368
    float* bnsh     = wsf + 559936;            // 2368
    float* rwT6     = wsf + 562304;            // 512
    float* shp25    = wsf + 564864;            // 64
    ushort_t* Wfrag = (ushort_t*)(wsf + 565248); // 1861632 shorts (3.7MB)

    float*    A0f = (float*)((char*)d_ws + (size_t)(16) * (1 << 20));
    float*    A1f = (float*)((char*)d_ws + (size_t)(80) * (1 << 20));
    float*    A2f = (float*)((char*)d_ws + (size_t)(144) * (1 << 20));
    ushort_t* A0s = (ushort_t*)A0f;
    ushort_t* A1s = (ushort_t*)A1f;
    ushort_t* A2s = (ushort_t*)A2f;

    static const int wfoff[36] = WFOFF_LIST;

    prep<<<20, 256, 0, stream>>>(bn_g, bn_b, bn_m, bn_v, res_w6, res_b12,
                                 bnsc, bnsh, rwT6, shp25);
    hyper_kernel<<<242, 256, 0, stream>>>(z_all, hn_w2, hn_b2, hn_w1, hn_b1, bnsc, Wg);
    split_w<<<dim3(168, 36), 256, 0, stream>>>(Wg, res_w12, Wfrag);
    conv_first<<<4096, 256, 0, stream>>>(x, conv1_w, conv1_b, bn_g, bn_b, bn_m, bn_v, A0f);

    // ---- stage 1: fp32, old path ----
    float* X = A0f; float* T1 = A1f; float* T2 = A2f;
    for (int i = 0; i < 6; ++i) {
        int L1 = 2 * i, L2 = 2 * i + 1;
        conv_mfma<16,16,32,1,16,16,0,1,1,0><<<4096, 256, 0, stream>>>(
            X, Wfrag + wfoff[L1], bnsh + (L1 + 1) * 64, nullptr, nullptr, nullptr, T1, nullptr);
        conv_mfma<16,16,32,1,16,16,1,1,1,0><<<4096, 256, 0, stream>>>(
            T1, Wfrag + wfoff[L2], bnsh + (L2 + 1) * 64, X, nullptr, nullptr, T2, nullptr);
        float* tmp = X; X = T2; T2 = tmp;
    }
    // X = A0f here.
    // ---- i = 6 transition ----
    conv_mfma<16,32,32,2,8,16,0,1,1,0><<<2048, 256, 0, stream>>>(
        A0f, Wfrag + wfoff[12], bnsh + 13 * 64, nullptr, nullptr, nullptr, A1f, nullptr);
    pad_zero<<<3264, 256, 0, stream>>>(A2s, 18, 12);
    conv_mfma<32,32,16,1,8,16,2,16,32,1><<<2048, 256, 0, stream>>>(
        A1f, Wfrag + wfoff[13], bnsh + 14 * 64, A0f, rwT6, res_b6, nullptr, A2s);
    pad_zero<<<3264, 256, 0, stream>>>(A1s, 18, 12);
    pad_zero<<<3264, 256, 0, stream>>>(A0s, 18, 12);

    // ---- stage 2: planes, conv_mx ----
    ushort_t* Xs = A2s; ushort_t* T1s = A1s; ushort_t* T2s = A0s;
    for (int i = 7; i < 12; ++i) {
        int L1 = 2 * i, L2 = 2 * i + 1;
        conv_mx<32,32,16,1,0,0,1,1,1><<<2048, 256, 0, stream>>>(
            Xs, Wfrag + wfoff[L1], bnsh + (L1 + 1) * 64, nullptr, T1s);
        conv_mx<32,32,16,1,1,0,1,1,1><<<2048, 256, 0, stream>>>(
            T1s, Wfrag + wfoff[L2], bnsh + (L2 + 1) * 64, Xs, T2s);
        ushort_t* tmp = Xs; Xs = T2s; T2s = tmp;
    }
    // Xs = A0s here.
    pad_zero<<<3456, 256, 0, stream>>>(A1s, 10, 24);
    pad_zero<<<3456, 256, 0, stream>>>(A2s, 10, 24);
    // ---- i = 12 transition ----
    conv_mx<32,64,16,2,0,0,1,1,1><<<1024, 256, 0, stream>>>(
        A0s, Wfrag + wfoff[24], bnsh + 25 * 64, nullptr, A1s);
    conv_mx<64,64,8,1,0,2,18,96,1><<<1024, 256, 0, stream>>>(
        A1s, Wfrag + wfoff[25], shp25, A0s, A2s);
    pad_zero<<<3456, 256, 0, stream>>>(A0s, 10, 24);

    // ---- stage 3 ----
    Xs = A2s; T1s = A1s; T2s = A0s;
    for (int i = 13; i < 18; ++i) {
        int L1 = 2 * i, L2 = 2 * i + 1;
        conv_mx<64,64,8,1,0,0,1,1,1><<<1024, 256, 0, stream>>>(
            Xs, Wfrag + wfoff[L1], bnsh + (L1 + 1) * 64, nullptr, T1s);
        conv_mx<64,64,8,1,1,0,1,1,1><<<1024, 256, 0, stream>>>(
            T1s, Wfrag + wfoff[L2], bnsh + (L2 + 1) * 64, Xs, T2s);
        ushort_t* tmp = Xs; Xs = T2s; T2s = tmp;
    }
    // Xs = A0s here.
    pool_fc<<<1024, 64, 0, stream>>>(Xs, fin_w, fin_b, outp);
}

// Round 7
// 1468.165 us; speedup vs baseline: 1.6755x; 1.6755x over previous
//
#include <hip/hip_runtime.h>
#include <hip/hip_bf16.h>

// ---------------------------------------------------------------------------
// Hypernetwork ResNet, bf16x3-split MFMA (fp32-equivalent precision).
// Stage 1 (16ch): fp32 NHWC global, LDS split, 16x16x32 MFMA (unchanged).
// Stages 2/3 (32/64ch): PADDED fp32 NHWC activations in global. conv_s23:
//   - stages block's input slab into LDS as bf16x3 [unit][slabpix] (split3
//     at staging; 16B/lane consecutive -> conflict-free ds_read/write)
//   - weights prefetched in CHUNK=5 k-step groups, ROLLED loop (unroll 1):
//     wA/wB cross the back-edge -> compiler cannot collapse the pipeline
//   - 32x32x16 MFMA; K-loop = ds_read + MFMA only (no global loads for A)
//   - i=12 1x1-s2 residual fused as 2 appended k-steps (res staged to LDS)
// ---------------------------------------------------------------------------

typedef __attribute__((ext_vector_type(8))) short bf16x8;
typedef __attribute__((ext_vector_type(4))) float f32x4;
typedef __attribute__((ext_vector_type(16))) float f32x16;
typedef unsigned short ushort_t;

#define OFFS_LIST {0,1,2,3,4,5,6,7,8,9,10,11,12,14,18,22,26,30,34,38,42,46,50,54,58,66,82,98,114,130,146,162,178,194,210,226,242}
#define K_LIST    {1,1,1,1,1,1,1,1,1,1,1,1,1,2,2,2,2,2,2,2,2,2,2,2,2,4,4,4,4,4,4,4,4,4,4,4}
#define H_LIST    {1,1,1,1,1,1,1,1,1,1,1,1,2,2,2,2,2,2,2,2,2,2,2,2,4,4,4,4,4,4,4,4,4,4,4,4}
#define WOFF_LIST {0,2304,4608,6912,9216,11520,13824,16128,18432,20736,23040,25344,27648,32256,41472,50688,59904,69120,78336,87552,96768,105984,115200,124416,133632,152064,188928,225792,262656,299520,336384,373248,410112,446976,483840,520704}
#define CIN_LIST  {16,16,16,16,16,16,16,16,16,16,16,16,16,32,32,32,32,32,32,32,32,32,32,32,32,64,64,64,64,64,64,64,64,64,64,64}
#define COUT_LIST {16,16,16,16,16,16,16,16,16,16,16,16,32,32,32,32,32,32,32,32,32,32,32,32,64,64,64,64,64,64,64,64,64,64,64,64}
#define WFOFF_LIST {0,7680,15360,23040,30720,38400,46080,53760,61440,69120,76800,84480,92160,107520,135168,165888,196608,227328,258048,288768,319488,350208,380928,411648,442368,503808,632832,755712,878592,1001472,1124352,1247232,1370112,1492992,1615872,1738752}

__constant__ int d_offs[37]  = OFFS_LIST;
__constant__ int d_k[36]     = K_LIST;
__constant__ int d_hh[36]    = H_LIST;
__constant__ int d_woff[36]  = WOFF_LIST;
__constant__ int d_cin[36]   = CIN_LIST;
__constant__ int d_cout[36]  = COUT_LIST;
__constant__ int d_wfoff[36] = WFOFF_LIST;

__device__ inline void split3(float x, ushort_t& h, ushort_t& m, ushort_t& l) {
    unsigned xb = __float_as_uint(x);
    unsigned hb = (xb + 0x8000u) >> 16;
    float fh = __uint_as_float(hb << 16);
    float r = x - fh;
    unsigned mb = (__float_as_uint(r) + 0x8000u) >> 16;
    float fm = __uint_as_float(mb << 16);
    float r2 = r - fm;
    unsigned lb = (__float_as_uint(r2) + 0x8000u) >> 16;
    h = (ushort_t)hb; m = (ushort_t)mb; l = (ushort_t)lb;
}

// --- prep: BN scale/shift, rwT6 transpose, shp25 = bnsh[26] + res_b12 -------
__global__ void prep(const float* __restrict__ g, const float* __restrict__ be,
                     const float* __restrict__ m, const float* __restrict__ v,
                     const float* __restrict__ rw6, const float* __restrict__ rb12,
                     float* __restrict__ sc, float* __restrict__ sh,
                     float* __restrict__ rwT6, float* __restrict__ shp25) {
    int i = blockIdx.x * blockDim.x + threadIdx.x;
    if (i < 2368) {
        float s = g[i] * rsqrtf(v[i] + 1e-5f);
        sc[i] = s;
        sh[i] = be[i] - m[i] * s;
    } else if (i < 2368 + 512) {
        int t = i - 2368;
        int co = t % 32, ci = t / 32;
        rwT6[ci * 32 + co] = rw6[co * 16 + ci];
    } else if (i < 2368 + 512 + 64) {
        int c = i - 2880;
        int idx2 = 26 * 64 + c;
        float s = g[idx2] * rsqrtf(v[idx2] + 1e-5f);
        shp25[c] = be[idx2] - m[idx2] * s + rb12[c];
    }
}

// --- Hypernetwork: one block per z-row. Emits fp32 weights [k][co]. ---------
__global__ void hyper_kernel(const float* __restrict__ z_all, const float* __restrict__ w2,
                             const float* __restrict__ b2, const float* __restrict__ w1,
                             const float* __restrict__ b1, const float* __restrict__ bnsc,
                             float* __restrict__ Wg) {
    int n = blockIdx.x;
    int tid = threadIdx.x;
    __shared__ float zrow[64];
    __shared__ float hin[1024];
    if (tid < 64) zrow[tid] = z_all[n * 64 + tid];
    __syncthreads();
    for (int mcol = tid; mcol < 1024; mcol += 256) {
        float acc = b2[mcol];
        #pragma unroll 8
        for (int d = 0; d < 64; ++d) acc += zrow[d] * w2[d * 1024 + mcol];
        hin[mcol] = acc;
    }
    __syncthreads();
    int L = 0;
    while (n >= d_offs[L + 1]) ++L;
    int r = n - d_offs[L];
    int kk = d_k[L];
    int a = r / kk, bb = r % kk;
    int Cin = kk * 16;
    int Cout = d_hh[L] * 16;
    const float* scp = bnsc + (L + 1) * 64;
    float* wp = Wg + d_woff[L];
    for (int e = tid; e < 2304; e += 256) {
        int i = e / 144, o = e % 144;
        int j = o / 9, tap = o % 9;
        float acc = b1[o];
        #pragma unroll 8
        for (int d = 0; d < 64; ++d) acc += hin[i * 64 + d] * w1[d * 144 + o];
        int co = a * 16 + i;
        acc *= scp[co];
        wp[(tap * Cin + (bb * 16 + j)) * Cout + co] = acc;
    }
}

// --- split weights into bf16x3 fragment blocks (two formats) ----------------
__global__ void split_w(const float* __restrict__ Wg, const float* __restrict__ rw12,
                        ushort_t* __restrict__ Wf) {
    int L = blockIdx.y;
    int CIN = d_cin[L], COUT = d_cout[L];
    int idx = blockIdx.x * 256 + threadIdx.x;
    int j = idx & 7, lane = (idx >> 3) & 63, t = idx >> 9;
    int hi = lane >> 5;
    float wv;
    int base;
    if (L < 14) {                       // 16x16x32 fragment format
        int K = 9 * CIN, NKS = (K + 31) / 32, NT = COUT / 16;
        if (t >= NKS * NT) return;
        int nt = t % NT, ks = t / NT;
        int k = ks * 32 + (lane >> 4) * 8 + j;
        int co = nt * 16 + (lane & 15);
        wv = (k < K) ? Wg[d_woff[L] + k * COUT + co] : 0.f;
        base = d_wfoff[L] + ((ks * NT + nt) * 3) * 512 + lane * 8 + j;
    } else {                            // 32x32x16, padded taps (10), tap-inner
        int CG8 = CIN / 8, NKS = 5 * CG8, NT = COUT / 32;
        int TKS = NKS + ((L == 25) ? 2 : 0);
        if (t >= TKS * NT) return;
        int nt = t % NT, ks = t / NT;
        int co = nt * 32 + (lane & 31);
        if (ks < NKS) {
            int o = 2 * ks + hi, tap = o % 10, c8 = o / 10;
            int ci = c8 * 8 + j;
            wv = (tap < 9) ? Wg[d_woff[L] + (tap * CIN + ci) * COUT + co] : 0.f;
        } else {                        // L25 appended 1x1-s2 residual weights
            int k = (ks - NKS) * 16 + hi * 8 + j;
            wv = rw12[co * 32 + k];
        }
        base = d_wfoff[L] + ((ks * NT + nt) * 3) * 512 + lane * 8 + j;
    }
    ushort_t h, m, l;
    split3(wv, h, m, l);
    Wf[base] = h; Wf[base + 512] = m; Wf[base + 1024] = l;
}

// --- First conv: 3->16, NCHW in -> NHWC fp32 out ----------------------------
__global__ void conv_first(const float* __restrict__ x, const float* __restrict__ cw,
                           const float* __restrict__ cb, const float* __restrict__ g,
                           const float* __restrict__ be, const float* __restrict__ m,
                           const float* __restrict__ v, float* __restrict__ out) {
    int idx = blockIdx.x * 256 + threadIdx.x;
    int px = idx & 31; int t = idx >> 5;
    int py = t & 31;   int b = t >> 5;
    float acc[16];
    #pragma unroll
    for (int co = 0; co < 16; ++co) acc[co] = 0.f;
    const float* ip = x + (long)b * 3 * 1024;
    #pragma unroll 1
    for (int ci = 0; ci < 3; ++ci) {
        #pragma unroll 1
        for (int ky = 0; ky < 3; ++ky) {
            int iy = py + ky - 1;
            if ((unsigned)iy >= 32u) continue;
            #pragma unroll
            for (int kx = 0; kx < 3; ++kx) {
                int ix = px + kx - 1;
                if ((unsigned)ix < 32u) {
                    float xv = ip[ci * 1024 + iy * 32 + ix];
                    #pragma unroll
                    for (int co = 0; co < 16; ++co)
                        acc[co] += xv * cw[co * 27 + ci * 9 + ky * 3 + kx];
                }
            }
        }
    }
    long o = ((long)(b * 32 + py) * 32 + px) * 16;
    #pragma unroll
    for (int co = 0; co < 16; ++co) {
        float s = g[co] * rsqrtf(v[co] + 1e-5f);
        float val = (acc[co] + cb[co] - m[co]) * s + be[co];
        out[o + co] = fmaxf(val, 0.f);
    }
}

// --- zero the halo ring of a padded fp32 NHWC buffer ------------------------
__global__ void pad_zero_f32(float* __restrict__ buf, int H2, int C4) {
    int idx = blockIdx.x * 256 + threadIdx.x;
    int nb = 2 * H2 + 2 * (H2 - 2);
    int total = 1024 * nb * C4;
    if (idx >= total) return;
    int ch = idx % C4; int t = idx / C4;
    int bp = t % nb; int img = t / nb;
    int y, x;
    if (bp < H2) { y = 0; x = bp; }
    else if (bp < 2 * H2) { y = H2 - 1; x = bp - H2; }
    else { int s = bp - 2 * H2; y = 1 + (s >> 1); x = (s & 1) ? H2 - 1 : 0; }
    long off = (((long)img * H2 + y) * H2 + x) * (C4 * 4) + ch * 4;
    *(float4*)(buf + off) = make_float4(0.f, 0.f, 0.f, 0.f);
}

// --- Stage-1 conv: 16x16x32 MFMA, LDS bf16x3 --------------------------------
// MODE 0: relu(conv+sh) | 1: +res fp32 | 2: +1x1s2(res fp32; rwT,rb)
// OUTF 0: fp32 NHWC unpadded out | 2: fp32 NHWC PADDED out ((HOUT+2)^2)
template<int CIN, int COUT, int HIN, int STRIDE, int TH, int TW, int MODE, int CR, int HR, int OUTF>
__global__ __launch_bounds__(256) void conv_mfma(
        const float* __restrict__ in, const ushort_t* __restrict__ wf,
        const float* __restrict__ shp, const float* __restrict__ res,
        const float* __restrict__ rwT, const float* __restrict__ rb,
        float* __restrict__ out) {
    constexpr int HOUT = HIN / STRIDE;
    constexpr int H2O = HOUT + 2;
    constexpr int CG8 = CIN / 8;
    constexpr int IH = (TH - 1) * STRIDE + 3;
    constexpr int IW = (TW - 1) * STRIDE + 3;
    constexpr int K = 9 * CIN;
    constexpr int NKS = (K + 31) / 32;
    constexpr bool TAIL = (K % 32) != 0;
    constexpr int NT = COUT / 16;
    constexpr int NMT = TH * TW / 16;
    constexpr int MTW = NMT / 4;
    constexpr int PADC = ((2 - (IH * IW)) % 8 + 8) % 8;
    constexpr int CSTU = IH * IW + PADC;
    constexpr int PST = CG8 * CSTU;
    constexpr int TX = HOUT / TW, TY = HOUT / TH;

    __shared__ uint4 lds[3 * PST];

    int tid = threadIdx.x;
    int bid = blockIdx.x;
    int tile = bid % (TY * TX);
    int b = bid / (TY * TX);
    int ty = tile / TX, tx = tile % TX;
    int Y0 = ty * TH, X0 = tx * TW;
    int gy0 = Y0 * STRIDE - 1, gx0 = X0 * STRIDE - 1;

    for (int e = tid; e < CG8 * IH * IW; e += 256) {
        int c8 = e / (IH * IW); int rr = e % (IH * IW);
        int ly = rr / IW, lx = rr % IW;
        int gy = gy0 + ly, gx = gx0 + lx;
        float vv[8];
        if ((unsigned)gy < (unsigned)HIN && (unsigned)gx < (unsigned)HIN) {
            const float4* p = (const float4*)(in + ((long)(b * HIN + gy) * HIN + gx) * CIN + c8 * 8);
            float4 a0 = p[0], a1 = p[1];
            vv[0]=a0.x; vv[1]=a0.y; vv[2]=a0.z; vv[3]=a0.w;
            vv[4]=a1.x; vv[5]=a1.y; vv[6]=a1.z; vv[7]=a1.w;
        } else {
            #pragma unroll
            for (int q = 0; q < 8; ++q) vv[q] = 0.f;
        }
        union { ushort_t u[8]; uint4 q4; } H, M, L;
        #pragma unroll
        for (int q = 0; q < 8; ++q) split3(vv[q], H.u[q], M.u[q], L.u[q]);
        int a16 = c8 * CSTU + rr;
        lds[a16] = H.q4; lds[PST + a16] = M.q4; lds[2 * PST + a16] = L.q4;
    }
    __syncthreads();

    int lane = tid & 63, wid = tid >> 6;
    int g = lane >> 4, r16 = lane & 15;

    f32x4 acc[MTW][NT] = {};

    int pbase[MTW];
    #pragma unroll
    for (int mt = 0; mt < MTW; ++mt) {
        int pid = (wid + 4 * mt) * 16 + r16;
        int py = pid / TW, px = pid % TW;
        pbase[mt] = (py * STRIDE) * IW + px * STRIDE;
    }

    #pragma unroll
    for (int ks = 0; ks < NKS; ++ks) {
        bf16x8 bfr[NT][3];
        #pragma unroll
        for (int nt = 0; nt < NT; ++nt)
            #pragma unroll
            for (int p = 0; p < 3; ++p)
                bfr[nt][p] = *(const bf16x8*)(wf + ((ks * NT + nt) * 3 + p) * 512 + lane * 8);

        int k0 = ks * 32 + g * 8;
        int tap = k0 / CIN;
        int ci8 = (k0 % CIN) >> 3;
        int ky = (tap * 11) >> 5;
        int kx = tap - 3 * ky;
        int ofs = ci8 * CSTU + ky * IW + kx;

        #pragma unroll
        for (int mt = 0; mt < MTW; ++mt) {
            int e16 = ofs + pbase[mt];
            if (TAIL && ks == NKS - 1) e16 = (g < 2) ? e16 : 0;
            const uint4* ap = lds + e16;
            bf16x8 ah = *(const bf16x8*)(ap);
            bf16x8 am = *(const bf16x8*)(ap + PST);
            bf16x8 al = *(const bf16x8*)(ap + 2 * PST);
            #pragma unroll
            for (int nt = 0; nt < NT; ++nt) {
                f32x4 c = acc[mt][nt];
                c = __builtin_amdgcn_mfma_f32_16x16x32_bf16(ah, bfr[nt][0], c, 0, 0, 0);
                c = __builtin_amdgcn_mfma_f32_16x16x32_bf16(ah, bfr[nt][1], c, 0, 0, 0);
                c = __builtin_amdgcn_mfma_f32_16x16x32_bf16(am, bfr[nt][0], c, 0, 0, 0);
                c = __builtin_amdgcn_mfma_f32_16x16x32_bf16(ah, bfr[nt][2], c, 0, 0, 0);
                c = __builtin_amdgcn_mfma_f32_16x16x32_bf16(am, bfr[nt][1], c, 0, 0, 0);
                c = __builtin_amdgcn_mfma_f32_16x16x32_bf16(al, bfr[nt][0], c, 0, 0, 0);
                acc[mt][nt] = c;
            }
        }
    }

    #pragma unroll
    for (int mt = 0; mt < MTW; ++mt) {
        #pragma unroll
        for (int nt = 0; nt < NT; ++nt) {
            int co = nt * 16 + r16;
            float shv = shp[co];
            #pragma unroll
            for (int reg = 0; reg < 4; ++reg) {
                int pid = (wid + 4 * mt) * 16 + g * 4 + reg;
                int py = pid / TW, px = pid % TW;
                int gy = Y0 + py, gx = X0 + px;
                float val = acc[mt][nt][reg] + shv;
                if (MODE == 1) {
                    long oidx = ((long)(b * HOUT + gy) * HOUT + gx) * COUT + co;
                    val += res[oidx];
                }
                if (MODE == 2) {
                    float racc = rb[co];
                    const float* rp = res + ((long)(b * HR + 2 * gy) * HR + 2 * gx) * CR;
                    #pragma unroll 4
                    for (int ci = 0; ci < CR; ++ci) racc += rp[ci] * rwT[ci * COUT + co];
                    val += racc;
                }
                val = fmaxf(val, 0.f);
                if (OUTF == 0) {
                    long oidx = ((long)(b * HOUT + gy) * HOUT + gx) * COUT + co;
                    out[oidx] = val;
                } else {
                    out[(((long)b * H2O + gy + 1) * H2O + gx + 1) * COUT + co] = val;
                }
            }
        }
    }
}

// --- Stages 2/3: LDS-slab conv, 32x32x16 MFMA, padded fp32 NHWC io ----------
// MODE 0: relu(conv+sh) | 1: + res (padded fp32, out geometry)
//      | 2: + 1x1-s2 residual via RKS appended k-steps (res: 18x18x32 padded)
template<int CIN, int COUT, int HIN, int STRIDE, int PXB, int MODE, int RKS, int CHUNK>
__global__ __launch_bounds__(256) void conv_s23(
        const float* __restrict__ in, const ushort_t* __restrict__ wf,
        const float* __restrict__ shp, const float* __restrict__ res,
        float* __restrict__ out) {
    constexpr int HOUT = HIN / STRIDE;
    constexpr int H2I = HIN + 2, H2O = HOUT + 2;
    constexpr int C8 = CIN / 8;
    constexpr int NKS = 5 * C8;
    constexpr int TKS = NKS + RKS;
    constexpr int NC = TKS / CHUNK;
    constexpr int NTT = COUT / 32;
    constexpr int ROWSB = PXB / HOUT;
    constexpr int SLABR = (ROWSB - 1) * STRIDE + 3;
    constexpr int SLABPIX = SLABR * H2I;
    constexpr int NBLK = HOUT / ROWSB;
    constexpr int RESU = 3 * C8 * SLABPIX;
    constexpr int LDSU = RESU + ((MODE == 2) ? 12 * 64 : 0);

    __shared__ uint4 lds[LDSU];

    int tid = threadIdx.x, lane = tid & 63, wid = tid >> 6;
    int lp = lane & 31, hi = lane >> 5;
    int bid = blockIdx.x;
    int img = bid / NBLK, blocky = bid % NBLK;
    int pxg = wid / NTT, ntb = wid % NTT;
    int pix0 = pxg * 32 + lp;
    int py_blk = pix0 / HOUT, px = pix0 % HOUT;
    int py = blocky * ROWSB + py_blk;
    int slabrow0 = blocky * ROWSB * STRIDE;

    const ushort_t* wfl = wf + lane * 8;

    bf16x8 wA[CHUNK][3], wB[CHUNK][3];
    auto LW = [&](int c, bf16x8 (&w)[CHUNK][3]) {
        #pragma unroll
        for (int i = 0; i < CHUNK; ++i) {
            int ks = c * CHUNK + i;
            #pragma unroll
            for (int pp = 0; pp < 3; ++pp)
                w[i][pp] = *(const bf16x8*)(wfl + ((ks * NTT + ntb) * 3 + pp) * 512);
        }
    };

    LW(0, wA);
    if (NC > 1) LW(1, wB);

    // ---- stage slab: padded fp32 -> split3 -> LDS bf16x3 [unit][slabpix] ----
    const float* ib = in + (long)img * H2I * H2I * CIN;
    for (int it = tid; it < SLABPIX * C8; it += 256) {
        int pix = it % SLABPIX, cc = it / SLABPIX;
        int sr = pix / H2I, sc = pix % H2I;
        const float* p4 = ib + ((long)(slabrow0 + sr) * H2I + sc) * CIN + cc * 8;
        float4 a0 = ((const float4*)p4)[0], a1 = ((const float4*)p4)[1];
        float vv[8] = {a0.x, a0.y, a0.z, a0.w, a1.x, a1.y, a1.z, a1.w};
        union { ushort_t u[8]; uint4 q; } H, M, L;
        #pragma unroll
        for (int q = 0; q < 8; ++q) split3(vv[q], H.u[q], M.u[q], L.u[q]);
        int u0 = cc * 3;
        lds[u0 * SLABPIX + pix] = H.q;
        lds[(u0 + 1) * SLABPIX + pix] = M.q;
        lds[(u0 + 2) * SLABPIX + pix] = L.q;
    }
    if (MODE == 2) {
        for (int it = tid; it < 256; it += 256) {
            int pix = it & 63, cc = it >> 6;
            int ry = pix >> 3, rx = pix & 7;
            const float* r4 = res + (((long)img * 18 + (2 * ry + 1)) * 18 + (2 * rx + 1)) * 32 + cc * 8;
            float4 a0 = ((const float4*)r4)[0], a1 = ((const float4*)r4)[1];
            float vv[8] = {a0.x, a0.y, a0.z, a0.w, a1.x, a1.y, a1.z, a1.w};
            union { ushort_t u[8]; uint4 q; } H, M, L;
            #pragma unroll
            for (int q = 0; q < 8; ++q) split3(vv[q], H.u[q], M.u[q], L.u[q]);
            int u0 = RESU + cc * 3 * 64;
            lds[u0 + pix] = H.q;
            lds[u0 + 64 + pix] = M.q;
            lds[u0 + 128 + pix] = L.q;
        }
    }
    __syncthreads();

    int pbase = (py_blk * STRIDE) * H2I + px * STRIDE;
    f32x16 acc = {};

    auto DOC = [&](int c, bf16x8 (&w)[CHUNK][3]) {
        #pragma unroll
        for (int i = 0; i < CHUNK; ++i) {
            int ks = c * CHUNK + i;
            bf16x8 x0, x1, x2;
            if (RKS > 0 && ks >= NKS) {
                int o2 = 2 * (ks - NKS) + hi;
                int a = RESU + o2 * 3 * 64 + pix0;
                x0 = *(const bf16x8*)&lds[a];
                x1 = *(const bf16x8*)&lds[a + 64];
                x2 = *(const bf16x8*)&lds[a + 128];
            } else {
                int o = 2 * ks + hi;
                int tap = o % 10, c8i = o / 10;
                int ky = (tap * 11) >> 5, kx = tap - 3 * ky;
                int t16 = (tap == 9) ? 0 : (ky * H2I + kx);
                int a = (c8i * 3) * SLABPIX + pbase + t16;
                x0 = *(const bf16x8*)&lds[a];
                x1 = *(const bf16x8*)&lds[a + SLABPIX];
                x2 = *(const bf16x8*)&lds[a + 2 * SLABPIX];
            }
            acc = __builtin_amdgcn_mfma_f32_32x32x16_bf16(w[i][0], x0, acc, 0, 0, 0);
            acc = __builtin_amdgcn_mfma_f32_32x32x16_bf16(w[i][1], x0, acc, 0, 0, 0);
            acc = __builtin_amdgcn_mfma_f32_32x32x16_bf16(w[i][0], x1, acc, 0, 0, 0);
            acc = __builtin_amdgcn_mfma_f32_32x32x16_bf16(w[i][2], x0, acc, 0, 0, 0);
            acc = __builtin_amdgcn_mfma_f32_32x32x16_bf16(w[i][1], x1, acc, 0, 0, 0);
            acc = __builtin_amdgcn_mfma_f32_32x32x16_bf16(w[i][0], x2, acc, 0, 0, 0);
        }
    };

    #pragma unroll 1
    for (int c = 0; c < NC; c += 2) {           // rolled: wA/wB cross back-edge
        DOC(c, wA);
        if (c + 2 < NC) LW(c + 2, wA);
        if (c + 1 < NC) DOC(c + 1, wB);
        if (c + 3 < NC) LW(c + 3, wB);
    }

    // ---- epilogue: row=(q&3)+8*(q>>2)+4*hi -> cout; col=lp -> pixel --------
    float* ob = out + (((long)img * H2O + py + 1) * H2O + (px + 1)) * COUT;
    const float* rb4 = (MODE == 1)
        ? res + (((long)img * H2O + py + 1) * H2O + (px + 1)) * COUT : nullptr;
    #pragma unroll
    for (int g = 0; g < 4; ++g) {
        int co = ntb * 32 + g * 8 + 4 * hi;
        float v0 = acc[4 * g + 0] + shp[co + 0];
        float v1 = acc[4 * g + 1] + shp[co + 1];
        float v2 = acc[4 * g + 2] + shp[co + 2];
        float v3 = acc[4 * g + 3] + shp[co + 3];
        if (MODE == 1) {
            float4 r = *(const float4*)(rb4 + co);
            v0 += r.x; v1 += r.y; v2 += r.z; v3 += r.w;
        }
        *(float4*)(ob + co) = make_float4(fmaxf(v0, 0.f), fmaxf(v1, 0.f),
                                          fmaxf(v2, 0.f), fmaxf(v3, 0.f));
    }
}

// --- avgpool (8x8, padded fp32 10x10x64) + FC (64->10) ----------------------
__global__ void pool_fc(const float* __restrict__ X, const float* __restrict__ fw,
                        const float* __restrict__ fb, float* __restrict__ out) {
    int b = blockIdx.x;
    int c = threadIdx.x;
    float s = 0.f;
    #pragma unroll
    for (int p = 0; p < 64; ++p) {
        int y = p >> 3, x = p & 7;
        s += X[(((long)b * 10 + y + 1) * 10 + (x + 1)) * 64 + c];
    }
    __shared__ float pooled[64];
    pooled[c] = s * (1.f / 64.f);
    __syncthreads();
    if (c < 10) {
        float acc = fb[c];
        #pragma unroll
        for (int k = 0; k < 64; ++k) acc += pooled[k] * fw[c * 64 + k];
        out[b * 10 + c] = acc;
    }
}

extern "C" void kernel_launch(void* const* d_in, const int* in_sizes, int n_in,
                              void* d_out, int out_size, void* d_ws, size_t ws_size,
                              hipStream_t stream) {
    const float* x       = (const float*)d_in[0];
    const float* conv1_w = (const float*)d_in[1];
    const float* conv1_b = (const float*)d_in[2];
    const float* bn_g    = (const float*)d_in[3];
    const float* bn_b    = (const float*)d_in[4];
    const float* bn_m    = (const float*)d_in[5];
    const float* bn_v    = (const float*)d_in[6];
    const float* hn_w2   = (const float*)d_in[7];
    const float* hn_b2   = (const float*)d_in[8];
    const float* hn_w1   = (const float*)d_in[9];
    const float* hn_b1   = (const float*)d_in[10];
    const float* z_all   = (const float*)d_in[11];
    const float* res_w6  = (const float*)d_in[12];
    const float* res_b6  = (const float*)d_in[13];
    const float* res_w12 = (const float*)d_in[14];
    const float* res_b12 = (const float*)d_in[15];
    const float* fin_w   = (const float*)d_in[16];
    const float* fin_b   = (const float*)d_in[17];
    float* outp = (float*)d_out;

    float* wsf      = (float*)d_ws;
    float* Wg       = wsf;                       // 557568 fp32
    float* bnsc     = wsf + 557568;
    float* bnsh     = wsf + 559936;
    float* rwT6     = wsf + 562304;
    float* shp25    = wsf + 564864;
    ushort_t* Wfrag = (ushort_t*)(wsf + 565248); // 1861632 shorts

    float* A0f = (float*)((char*)d_ws + (size_t)(16) * (1 << 20));
    float* A1f = (float*)((char*)d_ws + (size_t)(80) * (1 << 20));
    float* A2f = (float*)((char*)d_ws + (size_t)(144) * (1 << 20));

    static const int wfoff[36] = WFOFF_LIST;

    prep<<<20, 256, 0, stream>>>(bn_g, bn_b, bn_m, bn_v, res_w6, res_b12,
                                 bnsc, bnsh, rwT6, shp25);
    hyper_kernel<<<242, 256, 0, stream>>>(z_all, hn_w2, hn_b2, hn_w1, hn_b1, bnsc, Wg);
    split_w<<<dim3(168, 36), 256, 0, stream>>>(Wg, res_w12, Wfrag);
    conv_first<<<4096, 256, 0, stream>>>(x, conv1_w, conv1_b, bn_g, bn_b, bn_m, bn_v, A0f);

    // ---- stage 1: fp32 unpadded, 16x16x32 MFMA path ----
    float* X = A0f; float* T1 = A1f; float* T2 = A2f;
    for (int i = 0; i < 6; ++i) {
        int L1 = 2 * i, L2 = 2 * i + 1;
        conv_mfma<16,16,32,1,16,16,0,1,1,0><<<4096, 256, 0, stream>>>(
            X, Wfrag + wfoff[L1], bnsh + (L1 + 1) * 64, nullptr, nullptr, nullptr, T1);
        conv_mfma<16,16,32,1,16,16,1,1,1,0><<<4096, 256, 0, stream>>>(
            T1, Wfrag + wfoff[L2], bnsh + (L2 + 1) * 64, X, nullptr, nullptr, T2);
        float* tmp = X; X = T2; T2 = tmp;
    }
    // X = A0f here.
    // ---- i = 6 transition ----
    conv_mfma<16,32,32,2,8,16,0,1,1,0><<<2048, 256, 0, stream>>>(
        A0f, Wfrag + wfoff[12], bnsh + 13 * 64, nullptr, nullptr, nullptr, A1f);
    pad_zero_f32<<<2176, 256, 0, stream>>>(A2f, 18, 8);
    conv_mfma<32,32,16,1,8,16,2,16,32,2><<<2048, 256, 0, stream>>>(
        A1f, Wfrag + wfoff[13], bnsh + 14 * 64, A0f, rwT6, res_b6, A2f);
    pad_zero_f32<<<2176, 256, 0, stream>>>(A1f, 18, 8);
    pad_zero_f32<<<2176, 256, 0, stream>>>(A0f, 18, 8);

    // ---- stage 2: padded fp32, conv_s23 ----
    X = A2f; T1 = A1f; T2 = A0f;
    for (int i = 7; i < 12; ++i) {
        int L1 = 2 * i, L2 = 2 * i + 1;
        conv_s23<32,32,16,1,128,0,0,5><<<2048, 256, 0, stream>>>(
            X, Wfrag + wfoff[L1], bnsh + (L1 + 1) * 64, nullptr, T1);
        conv_s23<32,32,16,1,128,1,0,5><<<2048, 256, 0, stream>>>(
            T1, Wfrag + wfoff[L2], bnsh + (L2 + 1) * 64, X, T2);
        float* tmp = X; X = T2; T2 = tmp;
    }
    // X = A0f here.
    // ---- i = 12 transition ----
    pad_zero_f32<<<2304, 256, 0, stream>>>(A1f, 10, 16);
    conv_s23<32,64,16,2,64,0,0,5><<<1024, 256, 0, stream>>>(
        A0f, Wfrag + wfoff[24], bnsh + 25 * 64, nullptr, A1f);
    pad_zero_f32<<<2304, 256, 0, stream>>>(A2f, 10, 16);
    conv_s23<64,64,8,1,64,2,2,6><<<1024, 256, 0, stream>>>(
        A1f, Wfrag + wfoff[25], shp25, A0f, A2f);
    pad_zero_f32<<<2304, 256, 0, stream>>>(A0f, 10, 16);

    // ---- stage 3 ----
    X = A2f; T1 = A1f; T2 = A0f;
    for (int i = 13; i < 18; ++i) {
        int L1 = 2 * i, L2 = 2 * i + 1;
        conv_s23<64,64,8,1,64,0,0,5><<<1024, 256, 0, stream>>>(
            X, Wfrag + wfoff[L1], bnsh + (L1 + 1) * 64, nullptr, T1);
        conv_s23<64,64,8,1,64,1,0,5><<<1024, 256, 0, stream>>>(
            T1, Wfrag + wfoff[L2], bnsh + (L2 + 1) * 64, X, T2);
        float* tmp = X; X = T2; T2 = tmp;
    }
    // X = A0f here.
    pool_fc<<<1024, 64, 0, stream>>>(A0f, fin_w, fin_b, outp);
}